// Round 3
// baseline (106.780 us; speedup 1.0000x reference)
//
#include <hip/hip_runtime.h>
#include <math.h>

// Problem constants
#define NT 320
#define NS 16
#define PIN 8
#define MOUT 8
// step = TMAX/(NT-1)
#define STEPF (1.0f/319.0f)

// ---------------------------------------------------------------------------
// Wave-level 16x16 matmuls, fragment layout: lane l holds M[row][4*jb+m],
// row = l>>2, jb = l&3, m = 0..3 (one float4 per lane).
// ---------------------------------------------------------------------------

// C = A x B : C[i][4jb+m] = sum_k A[i][k]*B[k][4jb+m]
__device__ __forceinline__ float4 wave_mm(const float4 A, const float4 B,
                                          const int lane) {
    float4 c = make_float4(0.f, 0.f, 0.f, 0.f);
    const int rowbase = lane & 60;
    const int jb = lane & 3;
#pragma unroll
    for (int k = 0; k < 16; ++k) {
        const int srcA = rowbase | (k >> 2);
        float a;
        if ((k & 3) == 0)      a = __shfl(A.x, srcA);
        else if ((k & 3) == 1) a = __shfl(A.y, srcA);
        else if ((k & 3) == 2) a = __shfl(A.z, srcA);
        else                   a = __shfl(A.w, srcA);
        const int srcB = (k << 2) | jb;
        c.x += a * __shfl(B.x, srcB);
        c.y += a * __shfl(B.y, srcB);
        c.z += a * __shfl(B.z, srcB);
        c.w += a * __shfl(B.w, srcB);
    }
    return c;
}

// C = A x B^T : C[i][4jb+m] = sum_k A[i][k]*B[4jb+m][k]
__device__ __forceinline__ float4 wave_mm_abt(const float4 A, const float4 B,
                                              const int lane) {
    float4 c = make_float4(0.f, 0.f, 0.f, 0.f);
    const int rowbase = lane & 60;
    const int jb = lane & 3;
#pragma unroll
    for (int k = 0; k < 16; ++k) {
        const int hk = k >> 2;
        float a, b0, b1, b2, b3;
        if ((k & 3) == 0) {
            a  = __shfl(A.x, rowbase | hk);
            b0 = __shfl(B.x, (jb << 4) | 0 | hk);
            b1 = __shfl(B.x, (jb << 4) | 4 | hk);
            b2 = __shfl(B.x, (jb << 4) | 8 | hk);
            b3 = __shfl(B.x, (jb << 4) | 12 | hk);
        } else if ((k & 3) == 1) {
            a  = __shfl(A.y, rowbase | hk);
            b0 = __shfl(B.y, (jb << 4) | 0 | hk);
            b1 = __shfl(B.y, (jb << 4) | 4 | hk);
            b2 = __shfl(B.y, (jb << 4) | 8 | hk);
            b3 = __shfl(B.y, (jb << 4) | 12 | hk);
        } else if ((k & 3) == 2) {
            a  = __shfl(A.z, rowbase | hk);
            b0 = __shfl(B.z, (jb << 4) | 0 | hk);
            b1 = __shfl(B.z, (jb << 4) | 4 | hk);
            b2 = __shfl(B.z, (jb << 4) | 8 | hk);
            b3 = __shfl(B.z, (jb << 4) | 12 | hk);
        } else {
            a  = __shfl(A.w, rowbase | hk);
            b0 = __shfl(B.w, (jb << 4) | 0 | hk);
            b1 = __shfl(B.w, (jb << 4) | 4 | hk);
            b2 = __shfl(B.w, (jb << 4) | 8 | hk);
            b3 = __shfl(B.w, (jb << 4) | 12 | hk);
        }
        c.x += a * b0; c.y += a * b1; c.z += a * b2; c.w += a * b3;
    }
    return c;
}

// ---------------------------------------------------------------------------
// Phase 1: 320 blocks x 64 threads — ONE WAVE per time index k.
// Compute identical to the passing kernel; only CE is now stored TRANSPOSED
// (CE_t[ch*320 + k], ch = a*16 + l) so phase-2 reads coalesce over j.
// ---------------------------------------------------------------------------
__global__ __launch_bounds__(64) void k_phase1(
        const float* __restrict__ V1r,
        const float* __restrict__ V2r,
        const float* __restrict__ V3r,
        const float* __restrict__ C_w,
        const float* __restrict__ B_w,
        const float* __restrict__ cov0,
        const float* __restrict__ x0,
        float* __restrict__ CEt_g,
        float* __restrict__ Mrow_g,
        float* __restrict__ G_g,
        float* __restrict__ y1_g) {
    __shared__ float Msub[16][16];
    __shared__ float MinvT[16][16];
    __shared__ float V3s[16][16];
    const int lane = threadIdx.x;
    const int row = lane >> 2, jb = lane & 3;
    const int k = blockIdx.x;
    const float t = (float)k * STEPF;

    // --- load fragments ---
    const float4 v1 = *((const float4*)(V1r + row * 16 + jb * 4));
    const float4 v2 = *((const float4*)(V2r + row * 16 + jb * 4));
    const float4 v3raw = *((const float4*)(V3r + row * 16 + jb * 4));

    // M = tril(V1,-1) + |diag|+2eps ;  V2f = tril(V2)
    float4 Mf, V2f;
    {
        const float mv[4] = {v1.x, v1.y, v1.z, v1.w};
        const float vv[4] = {v2.x, v2.y, v2.z, v2.w};
        float mo[4], vo[4];
#pragma unroll
        for (int m = 0; m < 4; ++m) {
            const int col = jb * 4 + m;
            mo[m] = (row > col) ? mv[m]
                  : ((row == col) ? (fabsf(mv[m]) + 2.0f * 1e-3f) : 0.0f);
            vo[m] = (col <= row) ? vv[m] : 0.0f;
        }
        Mf  = make_float4(mo[0], mo[1], mo[2], mo[3]);
        V2f = make_float4(vo[0], vo[1], vo[2], vo[3]);
    }
    *((float4*)&Msub[row][jb * 4]) = Mf;
    *((float4*)&V3s[row][jb * 4])  = v3raw;
    __syncthreads();  // 1-wave block: compiles to a cheap waitcnt+barrier

    // --- forward substitution: column c = lane (V1 lower-triangular) ---
    if (lane < 16) {
        const int c = lane;
        float x[16];
#pragma unroll
        for (int r = 0; r < 16; ++r) {
            float s = (r == c) ? 1.0f : 0.0f;
#pragma unroll
            for (int kk = 0; kk < 16; ++kk) {
                if (kk < r) s -= Msub[r][kk] * x[kk];
            }
            x[r] = (r < c) ? 0.0f : s / Msub[r][r];
        }
#pragma unroll
        for (int r = 0; r < 16; ++r) MinvT[c][r] = x[r];
    }
    __syncthreads();

    // V3 fragment: V3[i][j] = (j>i)? V3r[i][j] : (i>j ? -V3r[j][i] : 0)
    float4 V3f;
    {
        float o[4];
#pragma unroll
        for (int m = 0; m < 4; ++m) {
            const int col = jb * 4 + m;
            const float up = V3s[row][col];
            const float lo = V3s[col][row];
            o[m] = (col > row) ? up : ((row > col) ? -lo : 0.0f);
        }
        V3f = make_float4(o[0], o[1], o[2], o[3]);
    }
    const float4 Tf = *((const float4*)&MinvT[row][jb * 4]);

    // Pinv = Minv^T Minv = T T^T ;  W = -0.5 V2 V2^T + V3 ;  A = Pinv W
    const float4 Pinvf = wave_mm_abt(Tf, Tf, lane);
    float4 Wf = wave_mm_abt(V2f, V2f, lane);
    Wf.x = -0.5f * Wf.x + V3f.x;
    Wf.y = -0.5f * Wf.y + V3f.y;
    Wf.z = -0.5f * Wf.z + V3f.z;
    Wf.w = -0.5f * Wf.w + V3f.w;
    const float4 Af = wave_mm(Pinvf, Wf, lane);

    // ||A||_inf via shuffle butterflies
    float s0 = fabsf(Af.x) + fabsf(Af.y) + fabsf(Af.z) + fabsf(Af.w);
    s0 += __shfl_xor(s0, 1);
    s0 += __shfl_xor(s0, 2);          // row sum in all 4 lanes of the row
    float nrm = s0;
    nrm = fmaxf(nrm, __shfl_xor(nrm, 4));
    nrm = fmaxf(nrm, __shfl_xor(nrm, 8));
    nrm = fmaxf(nrm, __shfl_xor(nrm, 16));
    nrm = fmaxf(nrm, __shfl_xor(nrm, 32));

    // scaling so ||A t / 2^s||_inf <= 0.5
    float nt = nrm * t;
    int s = 0;
    while (nt > 0.5f && s < 30) { nt *= 0.5f; ++s; }
    const float scale = t * exp2f((float)(-s));
    float4 Bh;
    Bh.x = Af.x * scale; Bh.y = Af.y * scale;
    Bh.z = Af.z * scale; Bh.w = Af.w * scale;

    // identity fragment
    float4 idf;
    idf.x = (row == 4 * jb + 0) ? 1.0f : 0.0f;
    idf.y = (row == 4 * jb + 1) ? 1.0f : 0.0f;
    idf.z = (row == 4 * jb + 2) ? 1.0f : 0.0f;
    idf.w = (row == 4 * jb + 3) ? 1.0f : 0.0f;

    // Horner: P = I + Bh/9 ; then P = I + (Bh P)/d for d = 8..1
    float4 P;
    P.x = idf.x + Bh.x * (1.0f / 9.0f);
    P.y = idf.y + Bh.y * (1.0f / 9.0f);
    P.z = idf.z + Bh.z * (1.0f / 9.0f);
    P.w = idf.w + Bh.w * (1.0f / 9.0f);
#pragma unroll
    for (int d = 8; d >= 1; --d) {
        const float4 c = wave_mm(Bh, P, lane);
        const float inv = 1.0f / (float)d;
        P.x = idf.x + c.x * inv;
        P.y = idf.y + c.y * inv;
        P.z = idf.z + c.z * inv;
        P.w = idf.w + c.w * inv;
    }
    for (int q = 0; q < s; ++q) P = wave_mm(P, P, lane);   // squarings

    // --- epilogue: CE = C@E (C padded to 16x16 by duplicating rows) ---
    const int crow = row & 7;
    const float4 Cf  = *((const float4*)(C_w + crow * 16 + jb * 4));
    const float4 CEf = wave_mm(Cf, P, lane);               // rows 0..7 valid
    const float4 covf = *((const float4*)(cov0 + row * 16 + jb * 4));
    const float4 Mrowf = wave_mm(CEf, covf, lane);         // rows 0..7 valid
    float4 Bwf = make_float4(0.f, 0.f, 0.f, 0.f);
    if (jb < 2) Bwf = *((const float4*)(B_w + row * 8 + jb * 4));
    const float4 Gf = wave_mm(CEf, Bwf, lane);             // rows<8, jb<2 valid
    const float4 x0f = *((const float4*)(x0 + jb * 4));
    float yp = CEf.x * x0f.x + CEf.y * x0f.y + CEf.z * x0f.z + CEf.w * x0f.w;
    yp += __shfl_xor(yp, 1);
    yp += __shfl_xor(yp, 2);                               // full dot in row lanes

    if (row < 8) {
        // CE stored TRANSPOSED: CE_t[ch][k], ch = row*16 + col (0..127)
        const int ch = row * 16 + jb * 4;
        CEt_g[(ch + 0) * 320 + k] = CEf.x;
        CEt_g[(ch + 1) * 320 + k] = CEf.y;
        CEt_g[(ch + 2) * 320 + k] = CEf.z;
        CEt_g[(ch + 3) * 320 + k] = CEf.w;
        *((float4*)(Mrow_g + k * 128 + row * 16 + jb * 4)) = Mrowf;
        if (jb < 2) *((float4*)(G_g + k * 64 + row * 8 + jb * 4)) = Gf;
        if (jb == 0) y1_g[k * 8 + row] = yp;
    }
}

// ---------------------------------------------------------------------------
// Phase 2: grid (640) x 320 thr.
//  bid <  320: covar1 row i (one thread per j, full 8x8 tile in registers).
//    ce reads are COALESCED b32 loads from transposed CE_t (lane index = j);
//    Mrow[i] is block-uniform -> scalar/broadcast loads.  Output transposed
//    through LDS (2 passes of 160 rows, 43.5 KB) into fully-contiguous
//    40 KB coalesced store sweeps.  Accumulation order == old kernel
//    (ascending l) -> bit-identical results.
//  bid >= 320: mean_y row i = bid-320 (old algorithm, 256 active threads).
// ---------------------------------------------------------------------------
__global__ __launch_bounds__(320) void k_phase2(
        const float* __restrict__ Mrow_g,
        const float* __restrict__ CEt_g,
        const float* __restrict__ y1_g,
        const float* __restrict__ G_g,
        const float* __restrict__ U,
        const float* __restrict__ dU,
        const float* __restrict__ D_w,
        float* __restrict__ out_c1,
        float* __restrict__ out_cu,
        float* __restrict__ out_mean) {
    const int bid = blockIdx.x;
    const int tid = threadIdx.x;

    if (bid < NT) {
        __shared__ float obuf[160 * 68];   // 43520 B, padded stride 17 float4
        const int i = bid;
        const int j = tid;                 // 0..319

        // covar_U (coalesced over j)
        {
            const float d = (float)(i - j) * STEPF;
            out_cu[i * 320 + j] = expf(-50.0f * d * d);  // LT=0.1 -> 50
        }

        const float* __restrict__ mi = Mrow_g + i * 128;   // block-uniform
        const float* __restrict__ ce = CEt_g + j;          // lane-coalesced
        float acc[8][8];
#pragma unroll
        for (int a = 0; a < 8; ++a)
#pragma unroll
            for (int b = 0; b < 8; ++b) acc[a][b] = 0.0f;

#pragma unroll
        for (int l = 0; l < 16; ++l) {
            float cv[8], mv[8];
#pragma unroll
            for (int b = 0; b < 8; ++b) cv[b] = ce[(b * 16 + l) * 320];
#pragma unroll
            for (int a = 0; a < 8; ++a) mv[a] = mi[a * 16 + l];
#pragma unroll
            for (int a = 0; a < 8; ++a)
#pragma unroll
                for (int b = 0; b < 8; ++b) acc[a][b] += mv[a] * cv[b];
        }

        // two-pass LDS transpose -> fully coalesced contiguous stores
        float4* __restrict__ dst = (float4*)(out_c1 + (size_t)i * 20480);
#pragma unroll
        for (int pass = 0; pass < 2; ++pass) {
            const int jr = j - 160 * pass;
            if (jr >= 0 && jr < 160) {
#pragma unroll
                for (int a = 0; a < 8; ++a) {
                    *((float4*)&obuf[jr * 68 + a * 8]) =
                        make_float4(acc[a][0], acc[a][1], acc[a][2], acc[a][3]);
                    *((float4*)&obuf[jr * 68 + a * 8 + 4]) =
                        make_float4(acc[a][4], acc[a][5], acc[a][6], acc[a][7]);
                }
            }
            __syncthreads();
#pragma unroll
            for (int r = 0; r < 8; ++r) {
                const int q  = tid + 320 * r;   // 0..2559 float4s
                const int jj = q >> 4, cc = q & 15;
                dst[pass * 2560 + q] = *((const float4*)&obuf[jj * 68 + cc * 4]);
            }
            __syncthreads();
        }
    } else {
        __shared__ float part[320];
        const int i  = bid - NT;
        const int m  = tid & 7;
        const int js = tid >> 3;
        float acc = 0.0f;
        if (tid < 256 && i > 0) {
            for (int j = js; j <= i; j += 32) {
                const float w = ((j == 0) || (j == i)) ? 0.5f : 1.0f;
                const float4* Gr = (const float4*)(G_g + (i - j) * 64 + m * 8);
                const float4* Ur = (const float4*)(U + j * 8);
                const float4 g0 = Gr[0], g1 = Gr[1];
                const float4 u0 = Ur[0], u1 = Ur[1];
                float d = g0.x * u0.x + g0.y * u0.y + g0.z * u0.z + g0.w * u0.w
                        + g1.x * u1.x + g1.y * u1.y + g1.z * u1.z + g1.w * u1.w;
                acc += w * d;
            }
        }
        part[tid] = (tid < 256) ? acc : 0.0f;
        __syncthreads();
#pragma unroll
        for (int off = 128; off >= 8; off >>= 1) {
            if (tid < off) part[tid] += part[tid + off];
            __syncthreads();
        }
        if (tid < 8) {
            float t3 = 0.0f;
#pragma unroll
            for (int p = 0; p < 8; ++p) t3 += D_w[tid * 8 + p] * dU[i * 8 + p];
            out_mean[i * 8 + tid] = y1_g[i * 8 + tid] + STEPF * part[tid] + t3;
        }
    }
}

// ---------------------------------------------------------------------------
extern "C" void kernel_launch(void* const* d_in, const int* in_sizes, int n_in,
                              void* d_out, int out_size, void* d_ws, size_t ws_size,
                              hipStream_t stream) {
    const float* V1r  = (const float*)d_in[0];
    const float* V2r  = (const float*)d_in[1];
    const float* V3r  = (const float*)d_in[2];
    const float* B_w  = (const float*)d_in[3];
    const float* C_w  = (const float*)d_in[4];
    const float* D_w  = (const float*)d_in[5];
    const float* x0   = (const float*)d_in[6];
    const float* cov0 = (const float*)d_in[7];
    const float* U    = (const float*)d_in[8];
    const float* dU   = (const float*)d_in[9];

    float* ws   = (float*)d_ws;
    float* CEt  = ws;             // 128*320 = 40960 (transposed)
    float* Mrow = CEt + 40960;    // 40960
    float* G    = Mrow + 40960;   // 320*64 = 20480
    float* y1   = G + 20480;      // 2560

    float* out      = (float*)d_out;
    float* out_mean = out;                      // 320*8
    float* out_c1   = out + 2560;               // 320*320*64
    float* out_cu   = out + 2560 + 320*320*64;  // 320*320

    k_phase1<<<NT, 64, 0, stream>>>(V1r, V2r, V3r, C_w, B_w, cov0, x0,
                                    CEt, Mrow, G, y1);
    k_phase2<<<2 * NT, 320, 0, stream>>>(Mrow, CEt, y1, G, U, dU, D_w,
                                         out_c1, out_cu, out_mean);
}

// Round 5
// 99.466 us; speedup vs baseline: 1.0735x; 1.0735x over previous
//
#include <hip/hip_runtime.h>
#include <math.h>

// Problem constants
#define NT 320
#define NS 16
#define PIN 8
#define MOUT 8
// step = TMAX/(NT-1)
#define STEPF (1.0f/319.0f)

// ---------------------------------------------------------------------------
// Wave-level 16x16 matmuls, fragment layout: lane l holds M[row][4*jb+m],
// row = l>>2, jb = l&3, m = 0..3 (one float4 per lane).
// ---------------------------------------------------------------------------

// C = A x B with B staged through LDS (double-buffered by caller).
// Replaces 64 B-side ds_bpermutes with 16 ds_read_b128 (conflict-free:
// 4 distinct 16B lines per k, 16-lane broadcast each).  FP order identical
// to the original shuffle version -> bit-identical results.
__device__ __forceinline__ float4 wave_mm_B(const float4 A, const float4 Bfrag,
                                            float* __restrict__ bb,
                                            const int lane) {
    *((float4*)&bb[(lane & 60) * 4 + (lane & 3) * 4]) = Bfrag;  // B[row][4jb..]
    __syncthreads();   // 1-wave block: waitcnt + cheap barrier
    float4 c = make_float4(0.f, 0.f, 0.f, 0.f);
    const int rowbase = lane & 60;
    const float4* __restrict__ brow = ((const float4*)bb) + (lane & 3);
#pragma unroll
    for (int k = 0; k < 16; ++k) {
        const int srcA = rowbase | (k >> 2);
        float a;
        if ((k & 3) == 0)      a = __shfl(A.x, srcA);
        else if ((k & 3) == 1) a = __shfl(A.y, srcA);
        else if ((k & 3) == 2) a = __shfl(A.z, srcA);
        else                   a = __shfl(A.w, srcA);
        const float4 b = brow[k * 4];          // ds_read_b128 offset:k*64
        c.x += a * b.x;
        c.y += a * b.y;
        c.z += a * b.z;
        c.w += a * b.w;
    }
    return c;
}

// C = A x B^T : C[i][4jb+m] = sum_k A[i][k]*B[4jb+m][k]  (2 uses, unchanged)
__device__ __forceinline__ float4 wave_mm_abt(const float4 A, const float4 B,
                                              const int lane) {
    float4 c = make_float4(0.f, 0.f, 0.f, 0.f);
    const int rowbase = lane & 60;
    const int jb = lane & 3;
#pragma unroll
    for (int k = 0; k < 16; ++k) {
        const int hk = k >> 2;
        float a, b0, b1, b2, b3;
        if ((k & 3) == 0) {
            a  = __shfl(A.x, rowbase | hk);
            b0 = __shfl(B.x, (jb << 4) | 0 | hk);
            b1 = __shfl(B.x, (jb << 4) | 4 | hk);
            b2 = __shfl(B.x, (jb << 4) | 8 | hk);
            b3 = __shfl(B.x, (jb << 4) | 12 | hk);
        } else if ((k & 3) == 1) {
            a  = __shfl(A.y, rowbase | hk);
            b0 = __shfl(B.y, (jb << 4) | 0 | hk);
            b1 = __shfl(B.y, (jb << 4) | 4 | hk);
            b2 = __shfl(B.y, (jb << 4) | 8 | hk);
            b3 = __shfl(B.y, (jb << 4) | 12 | hk);
        } else if ((k & 3) == 2) {
            a  = __shfl(A.z, rowbase | hk);
            b0 = __shfl(B.z, (jb << 4) | 0 | hk);
            b1 = __shfl(B.z, (jb << 4) | 4 | hk);
            b2 = __shfl(B.z, (jb << 4) | 8 | hk);
            b3 = __shfl(B.z, (jb << 4) | 12 | hk);
        } else {
            a  = __shfl(A.w, rowbase | hk);
            b0 = __shfl(B.w, (jb << 4) | 0 | hk);
            b1 = __shfl(B.w, (jb << 4) | 4 | hk);
            b2 = __shfl(B.w, (jb << 4) | 8 | hk);
            b3 = __shfl(B.w, (jb << 4) | 12 | hk);
        }
        c.x += a * b0; c.y += a * b1; c.z += a * b2; c.w += a * b3;
    }
    return c;
}

// ---------------------------------------------------------------------------
// Phase 1: 320 blocks x 64 threads — ONE WAVE per time index k.
// Math identical to the 102.0-µs kernel (bit-identical fma order); the B
// operand of every square matmul now comes from LDS (wave_mm_B).
// ---------------------------------------------------------------------------
__global__ __launch_bounds__(64) void k_phase1(
        const float* __restrict__ V1r,
        const float* __restrict__ V2r,
        const float* __restrict__ V3r,
        const float* __restrict__ C_w,
        const float* __restrict__ B_w,
        const float* __restrict__ cov0,
        const float* __restrict__ x0,
        float* __restrict__ CE_g,
        float* __restrict__ Mrow_g,
        float* __restrict__ G_g,
        float* __restrict__ y1_g) {
    __shared__ float Msub[16][16];
    __shared__ float MinvT[16][16];
    __shared__ float V3s[16][16];
    __shared__ float Bbuf0[256];
    __shared__ float Bbuf1[256];
    const int lane = threadIdx.x;
    const int row = lane >> 2, jb = lane & 3;
    const int k = blockIdx.x;
    const float t = (float)k * STEPF;

    int tog = 0;

    // --- load fragments ---
    const float4 v1 = *((const float4*)(V1r + row * 16 + jb * 4));
    const float4 v2 = *((const float4*)(V2r + row * 16 + jb * 4));
    const float4 v3raw = *((const float4*)(V3r + row * 16 + jb * 4));

    // M = tril(V1,-1) + |diag|+2eps ;  V2f = tril(V2)
    float4 Mf, V2f;
    {
        const float mv[4] = {v1.x, v1.y, v1.z, v1.w};
        const float vv[4] = {v2.x, v2.y, v2.z, v2.w};
        float mo[4], vo[4];
#pragma unroll
        for (int m = 0; m < 4; ++m) {
            const int col = jb * 4 + m;
            mo[m] = (row > col) ? mv[m]
                  : ((row == col) ? (fabsf(mv[m]) + 2.0f * 1e-3f) : 0.0f);
            vo[m] = (col <= row) ? vv[m] : 0.0f;
        }
        Mf  = make_float4(mo[0], mo[1], mo[2], mo[3]);
        V2f = make_float4(vo[0], vo[1], vo[2], vo[3]);
    }
    *((float4*)&Msub[row][jb * 4]) = Mf;
    *((float4*)&V3s[row][jb * 4])  = v3raw;
    __syncthreads();

    // --- forward substitution: column c = lane (V1 lower-triangular) ---
    if (lane < 16) {
        const int c = lane;
        float x[16];
#pragma unroll
        for (int r = 0; r < 16; ++r) {
            float s = (r == c) ? 1.0f : 0.0f;
#pragma unroll
            for (int kk = 0; kk < 16; ++kk) {
                if (kk < r) s -= Msub[r][kk] * x[kk];
            }
            x[r] = (r < c) ? 0.0f : s / Msub[r][r];
        }
#pragma unroll
        for (int r = 0; r < 16; ++r) MinvT[c][r] = x[r];
    }
    __syncthreads();

    // V3 fragment: V3[i][j] = (j>i)? V3r[i][j] : (i>j ? -V3r[j][i] : 0)
    float4 V3f;
    {
        float o[4];
#pragma unroll
        for (int m = 0; m < 4; ++m) {
            const int col = jb * 4 + m;
            const float up = V3s[row][col];
            const float lo = V3s[col][row];
            o[m] = (col > row) ? up : ((row > col) ? -lo : 0.0f);
        }
        V3f = make_float4(o[0], o[1], o[2], o[3]);
    }
    const float4 Tf = *((const float4*)&MinvT[row][jb * 4]);

    // Pinv = Minv^T Minv = T T^T ;  W = -0.5 V2 V2^T + V3 ;  A = Pinv W
    const float4 Pinvf = wave_mm_abt(Tf, Tf, lane);
    float4 Wf = wave_mm_abt(V2f, V2f, lane);
    Wf.x = -0.5f * Wf.x + V3f.x;
    Wf.y = -0.5f * Wf.y + V3f.y;
    Wf.z = -0.5f * Wf.z + V3f.z;
    Wf.w = -0.5f * Wf.w + V3f.w;
    const float4 Af = wave_mm_B(Pinvf, Wf, tog ? Bbuf1 : Bbuf0, lane); tog ^= 1;

    // ||A||_inf via shuffle butterflies
    float s0 = fabsf(Af.x) + fabsf(Af.y) + fabsf(Af.z) + fabsf(Af.w);
    s0 += __shfl_xor(s0, 1);
    s0 += __shfl_xor(s0, 2);          // row sum in all 4 lanes of the row
    float nrm = s0;
    nrm = fmaxf(nrm, __shfl_xor(nrm, 4));
    nrm = fmaxf(nrm, __shfl_xor(nrm, 8));
    nrm = fmaxf(nrm, __shfl_xor(nrm, 16));
    nrm = fmaxf(nrm, __shfl_xor(nrm, 32));

    // scaling so ||A t / 2^s||_inf <= 0.5
    float nt = nrm * t;
    int s = 0;
    while (nt > 0.5f && s < 30) { nt *= 0.5f; ++s; }
    const float scale = t * exp2f((float)(-s));
    float4 Bh;
    Bh.x = Af.x * scale; Bh.y = Af.y * scale;
    Bh.z = Af.z * scale; Bh.w = Af.w * scale;

    // identity fragment
    float4 idf;
    idf.x = (row == 4 * jb + 0) ? 1.0f : 0.0f;
    idf.y = (row == 4 * jb + 1) ? 1.0f : 0.0f;
    idf.z = (row == 4 * jb + 2) ? 1.0f : 0.0f;
    idf.w = (row == 4 * jb + 3) ? 1.0f : 0.0f;

    // Horner: P = I + Bh/9 ; then P = I + (Bh P)/d for d = 8..1
    float4 P;
    P.x = idf.x + Bh.x * (1.0f / 9.0f);
    P.y = idf.y + Bh.y * (1.0f / 9.0f);
    P.z = idf.z + Bh.z * (1.0f / 9.0f);
    P.w = idf.w + Bh.w * (1.0f / 9.0f);
#pragma unroll
    for (int d = 8; d >= 1; --d) {
        const float4 c = wave_mm_B(Bh, P, tog ? Bbuf1 : Bbuf0, lane); tog ^= 1;
        const float inv = 1.0f / (float)d;
        P.x = idf.x + c.x * inv;
        P.y = idf.y + c.y * inv;
        P.z = idf.z + c.z * inv;
        P.w = idf.w + c.w * inv;
    }
    for (int q = 0; q < s; ++q) {           // squarings
        P = wave_mm_B(P, P, tog ? Bbuf1 : Bbuf0, lane); tog ^= 1;
    }

    // --- epilogue: CE = C@E (C padded to 16x16 by duplicating rows) ---
    const int crow = row & 7;
    const float4 Cf  = *((const float4*)(C_w + crow * 16 + jb * 4));
    const float4 CEf = wave_mm_B(Cf, P, tog ? Bbuf1 : Bbuf0, lane); tog ^= 1;
    const float4 covf = *((const float4*)(cov0 + row * 16 + jb * 4));
    const float4 Mrowf = wave_mm_B(CEf, covf, tog ? Bbuf1 : Bbuf0, lane); tog ^= 1;
    float4 Bwf = make_float4(0.f, 0.f, 0.f, 0.f);
    if (jb < 2) Bwf = *((const float4*)(B_w + row * 8 + jb * 4));
    const float4 Gf = wave_mm_B(CEf, Bwf, tog ? Bbuf1 : Bbuf0, lane); tog ^= 1;
    const float4 x0f = *((const float4*)(x0 + jb * 4));
    float yp = CEf.x * x0f.x + CEf.y * x0f.y + CEf.z * x0f.z + CEf.w * x0f.w;
    yp += __shfl_xor(yp, 1);
    yp += __shfl_xor(yp, 2);                // full dot in row lanes

    if (row < 8) {
        *((float4*)(CE_g   + k * 128 + row * 16 + jb * 4)) = CEf;
        *((float4*)(Mrow_g + k * 128 + row * 16 + jb * 4)) = Mrowf;
        if (jb < 2) *((float4*)(G_g + k * 64 + row * 8 + jb * 4)) = Gf;
        if (jb == 0) y1_g[k * 8 + row] = yp;
    }
}

// ---------------------------------------------------------------------------
// Phase 2 (fused covar + mean): grid (11, 320) x 256 thr.  VERBATIM the
// 102.0-µs round-1 version (padded LDS strides, 2-row register blocking).
// ---------------------------------------------------------------------------
#define CEP 132   // padded CE row stride in floats (132 mod 32 = 4)
#define MIP 20    // padded Mi row stride in floats (20a mod 32 distinct)

__global__ void k_phase2(const float* __restrict__ Mrow_g,
                         const float* __restrict__ CE_g,
                         const float* __restrict__ y1_g,
                         const float* __restrict__ G_g,
                         const float* __restrict__ U,
                         const float* __restrict__ dU,
                         const float* __restrict__ D_w,
                         float* __restrict__ out_c1,
                         float* __restrict__ out_cu,
                         float* __restrict__ out_mean) {
    const int bx  = blockIdx.x;   // 0..10
    const int i   = blockIdx.y;   // 0..319
    const int tid = threadIdx.x;

    if (bx < 10) {
        __shared__ float CEj[32 * CEP];   // 16896 B, padded
        __shared__ float Mi[8 * MIP];     // 640 B, padded
        const int jg = bx;
        {   // staging: 32 j-rows of 128 floats -> padded rows of CEP
            const float4* srcC = (const float4*)(CE_g + jg * 4096);
#pragma unroll
            for (int r = 0; r < 4; ++r) {
                const int t = tid + 256 * r;   // 0..1023 float4s
                const int j = t >> 5;          // 0..31
                const int q = t & 31;          // float4 within row
                *((float4*)&CEj[j * CEP + q * 4]) = srcC[t];
            }
            if (tid < 32) {
                const int a = tid >> 2, q = tid & 3;
                *((float4*)&Mi[a * MIP + q * 4]) =
                    ((const float4*)(Mrow_g + i * 128))[tid];
            }
        }
        __syncthreads();

        const int jj  = tid >> 3;         // 0..31
        const int rem = tid & 7;
        const int a0  = rem >> 1;         // 0..3 (this thread also does a0+4)
        const int bg  = rem & 1;          // 0..1 (4 b's each)
        const float* ce = CEj + jj * CEP + bg * 64;
        const float* m0 = Mi + a0 * MIP;
        const float* m1 = Mi + (a0 + 4) * MIP;
        float r0[4], r1[4];
#pragma unroll
        for (int b = 0; b < 4; ++b) {
            float acc0 = 0.0f, acc1 = 0.0f;
#pragma unroll
            for (int l = 0; l < 16; ++l) {
                const float c = ce[b * 16 + l];
                acc0 += m0[l] * c;
                acc1 += m1[l] * c;
            }
            r0[b] = acc0; r1[b] = acc1;
        }
        const int j = jg * 32 + jj;
        float* dst = out_c1 + ((size_t)(i * 320 + j)) * 64;
        *((float4*)(dst + a0 * 8 + bg * 4)) =
            make_float4(r0[0], r0[1], r0[2], r0[3]);
        *((float4*)(dst + (a0 + 4) * 8 + bg * 4)) =
            make_float4(r1[0], r1[1], r1[2], r1[3]);

        if (tid < 32) {
            const int jx = jg * 32 + tid;
            const float d = (float)(i - jx) * STEPF;
            out_cu[i * 320 + jx] = expf(-50.0f * d * d);  // LT=0.1 -> 50
        }
    } else {
        __shared__ float part[256];
        const int m  = tid & 7;
        const int js = tid >> 3;          // 0..31
        float acc = 0.0f;
        if (i > 0) {
            for (int j = js; j <= i; j += 32) {
                const float w = ((j == 0) || (j == i)) ? 0.5f : 1.0f;
                const float4* Gr = (const float4*)(G_g + (i - j) * 64 + m * 8);
                const float4* Ur = (const float4*)(U + j * 8);
                const float4 g0 = Gr[0], g1 = Gr[1];
                const float4 u0 = Ur[0], u1 = Ur[1];
                float d = g0.x * u0.x + g0.y * u0.y + g0.z * u0.z + g0.w * u0.w
                        + g1.x * u1.x + g1.y * u1.y + g1.z * u1.z + g1.w * u1.w;
                acc += w * d;
            }
        }
        part[tid] = acc;
        __syncthreads();
#pragma unroll
        for (int off = 128; off >= 8; off >>= 1) {
            if (tid < off) part[tid] += part[tid + off];
            __syncthreads();
        }
        if (tid < 8) {
            float t3 = 0.0f;
#pragma unroll
            for (int p = 0; p < 8; ++p) t3 += D_w[tid * 8 + p] * dU[i * 8 + p];
            out_mean[i * 8 + tid] = y1_g[i * 8 + tid] + STEPF * part[tid] + t3;
        }
    }
}

// ---------------------------------------------------------------------------
extern "C" void kernel_launch(void* const* d_in, const int* in_sizes, int n_in,
                              void* d_out, int out_size, void* d_ws, size_t ws_size,
                              hipStream_t stream) {
    const float* V1r  = (const float*)d_in[0];
    const float* V2r  = (const float*)d_in[1];
    const float* V3r  = (const float*)d_in[2];
    const float* B_w  = (const float*)d_in[3];
    const float* C_w  = (const float*)d_in[4];
    const float* D_w  = (const float*)d_in[5];
    const float* x0   = (const float*)d_in[6];
    const float* cov0 = (const float*)d_in[7];
    const float* U    = (const float*)d_in[8];
    const float* dU   = (const float*)d_in[9];

    float* ws   = (float*)d_ws;
    float* CE   = ws;             // 320*128 = 40960
    float* Mrow = CE + 40960;     // 40960
    float* G    = Mrow + 40960;   // 320*64 = 20480
    float* y1   = G + 20480;      // 2560

    float* out      = (float*)d_out;
    float* out_mean = out;                      // 320*8
    float* out_c1   = out + 2560;               // 320*320*64
    float* out_cu   = out + 2560 + 320*320*64;  // 320*320

    k_phase1<<<NT, 64, 0, stream>>>(V1r, V2r, V3r, C_w, B_w, cov0, x0,
                                    CE, Mrow, G, y1);
    k_phase2<<<dim3(11, NT), 256, 0, stream>>>(Mrow, CE, y1, G, U, dU, D_w,
                                               out_c1, out_cu, out_mean);
}

// Round 6
// 96.916 us; speedup vs baseline: 1.1018x; 1.0263x over previous
//
#include <hip/hip_runtime.h>
#include <math.h>

// Problem constants
#define NT 320
#define NS 16
#define PIN 8
#define MOUT 8
// step = TMAX/(NT-1)
#define STEPF (1.0f/319.0f)

// ---------------------------------------------------------------------------
// Wave-level 16x16 matmuls, fragment layout: lane l holds M[row][4*jb+m],
// row = l>>2, jb = l&3, m = 0..3 (one float4 per lane).
//
// New scheme (bit-identical FP order vs the shuffle version):
//   stage_frag : write this lane's fragment to LDS + barrier
//   load_rows  : read this lane's full 16-float row (4x ds_read_b128,
//                broadcast within each 4-lane row group)
//   mm_rows    : C[row][4jb+m] = sum_k arow[k] * B[k][4jb+m], B from LDS
// ---------------------------------------------------------------------------

__device__ __forceinline__ void stage_frag(const float4 f,
                                           float* __restrict__ bb,
                                           const int lane) {
    *((float4*)&bb[(lane & 60) * 4 + (lane & 3) * 4]) = f;   // M[row][4jb..]
    __syncthreads();   // 1-wave block: waitcnt + cheap barrier
}

__device__ __forceinline__ void load_rows(const float* __restrict__ bb,
                                          const int lane, float4 ar[4]) {
    const float4* __restrict__ rr = (const float4*)(bb + (lane & 60) * 4);
#pragma unroll
    for (int q = 0; q < 4; ++q) ar[q] = rr[q];   // A[row][0..15], broadcast
}

__device__ __forceinline__ float4 mm_rows(const float4 ar[4],
                                          const float* __restrict__ bb,
                                          const int lane) {
    float4 c = make_float4(0.f, 0.f, 0.f, 0.f);
    const float4* __restrict__ brow = ((const float4*)bb) + (lane & 3);
#pragma unroll
    for (int k = 0; k < 16; ++k) {
        const float4 aq = ar[k >> 2];
        const float a = ((k & 3) == 0) ? aq.x
                      : ((k & 3) == 1) ? aq.y
                      : ((k & 3) == 2) ? aq.z : aq.w;
        const float4 b = brow[k * 4];          // ds_read_b128 offset:k*64
        c.x += a * b.x;
        c.y += a * b.y;
        c.z += a * b.z;
        c.w += a * b.w;
    }
    return c;
}

// C = A x B^T : C[i][4jb+m] = sum_k A[i][k]*B[4jb+m][k]  (2 uses, unchanged)
__device__ __forceinline__ float4 wave_mm_abt(const float4 A, const float4 B,
                                              const int lane) {
    float4 c = make_float4(0.f, 0.f, 0.f, 0.f);
    const int rowbase = lane & 60;
    const int jb = lane & 3;
#pragma unroll
    for (int k = 0; k < 16; ++k) {
        const int hk = k >> 2;
        float a, b0, b1, b2, b3;
        if ((k & 3) == 0) {
            a  = __shfl(A.x, rowbase | hk);
            b0 = __shfl(B.x, (jb << 4) | 0 | hk);
            b1 = __shfl(B.x, (jb << 4) | 4 | hk);
            b2 = __shfl(B.x, (jb << 4) | 8 | hk);
            b3 = __shfl(B.x, (jb << 4) | 12 | hk);
        } else if ((k & 3) == 1) {
            a  = __shfl(A.y, rowbase | hk);
            b0 = __shfl(B.y, (jb << 4) | 0 | hk);
            b1 = __shfl(B.y, (jb << 4) | 4 | hk);
            b2 = __shfl(B.y, (jb << 4) | 8 | hk);
            b3 = __shfl(B.y, (jb << 4) | 12 | hk);
        } else if ((k & 3) == 2) {
            a  = __shfl(A.z, rowbase | hk);
            b0 = __shfl(B.z, (jb << 4) | 0 | hk);
            b1 = __shfl(B.z, (jb << 4) | 4 | hk);
            b2 = __shfl(B.z, (jb << 4) | 8 | hk);
            b3 = __shfl(B.z, (jb << 4) | 12 | hk);
        } else {
            a  = __shfl(A.w, rowbase | hk);
            b0 = __shfl(B.w, (jb << 4) | 0 | hk);
            b1 = __shfl(B.w, (jb << 4) | 4 | hk);
            b2 = __shfl(B.w, (jb << 4) | 8 | hk);
            b3 = __shfl(B.w, (jb << 4) | 12 | hk);
        }
        c.x += a * b0; c.y += a * b1; c.z += a * b2; c.w += a * b3;
    }
    return c;
}

// ---------------------------------------------------------------------------
// Phase 1: 320 blocks x 64 threads — ONE WAVE per time index k.
// Math identical (bit-identical fma order); A-side shuffles replaced by
// one-time row staging: Horner's A (=Bh) rows read once, squarings share
// one staging for A and B, CE's A-row loaded from global, Mrow/G share CEf.
// ---------------------------------------------------------------------------
__global__ __launch_bounds__(64) void k_phase1(
        const float* __restrict__ V1r,
        const float* __restrict__ V2r,
        const float* __restrict__ V3r,
        const float* __restrict__ C_w,
        const float* __restrict__ B_w,
        const float* __restrict__ cov0,
        const float* __restrict__ x0,
        float* __restrict__ CE_g,
        float* __restrict__ Mrow_g,
        float* __restrict__ G_g,
        float* __restrict__ y1_g) {
    __shared__ float Msub[16][16];
    __shared__ float MinvT[16][16];
    __shared__ float V3s[16][16];
    __shared__ float Bbuf0[256];
    __shared__ float Bbuf1[256];
    const int lane = threadIdx.x;
    const int row = lane >> 2, jb = lane & 3;
    const int k = blockIdx.x;
    const float t = (float)k * STEPF;

    int tog = 0;

    // --- load fragments ---
    const float4 v1 = *((const float4*)(V1r + row * 16 + jb * 4));
    const float4 v2 = *((const float4*)(V2r + row * 16 + jb * 4));
    const float4 v3raw = *((const float4*)(V3r + row * 16 + jb * 4));

    // M = tril(V1,-1) + |diag|+2eps ;  V2f = tril(V2)
    float4 Mf, V2f;
    {
        const float mv[4] = {v1.x, v1.y, v1.z, v1.w};
        const float vv[4] = {v2.x, v2.y, v2.z, v2.w};
        float mo[4], vo[4];
#pragma unroll
        for (int m = 0; m < 4; ++m) {
            const int col = jb * 4 + m;
            mo[m] = (row > col) ? mv[m]
                  : ((row == col) ? (fabsf(mv[m]) + 2.0f * 1e-3f) : 0.0f);
            vo[m] = (col <= row) ? vv[m] : 0.0f;
        }
        Mf  = make_float4(mo[0], mo[1], mo[2], mo[3]);
        V2f = make_float4(vo[0], vo[1], vo[2], vo[3]);
    }
    *((float4*)&Msub[row][jb * 4]) = Mf;
    *((float4*)&V3s[row][jb * 4])  = v3raw;
    __syncthreads();

    // --- forward substitution: column c = lane (V1 lower-triangular) ---
    if (lane < 16) {
        const int c = lane;
        float x[16];
#pragma unroll
        for (int r = 0; r < 16; ++r) {
            float s = (r == c) ? 1.0f : 0.0f;
#pragma unroll
            for (int kk = 0; kk < 16; ++kk) {
                if (kk < r) s -= Msub[r][kk] * x[kk];
            }
            x[r] = (r < c) ? 0.0f : s / Msub[r][r];
        }
#pragma unroll
        for (int r = 0; r < 16; ++r) MinvT[c][r] = x[r];
    }
    __syncthreads();

    // V3 fragment: V3[i][j] = (j>i)? V3r[i][j] : (i>j ? -V3r[j][i] : 0)
    float4 V3f;
    {
        float o[4];
#pragma unroll
        for (int m = 0; m < 4; ++m) {
            const int col = jb * 4 + m;
            const float up = V3s[row][col];
            const float lo = V3s[col][row];
            o[m] = (col > row) ? up : ((row > col) ? -lo : 0.0f);
        }
        V3f = make_float4(o[0], o[1], o[2], o[3]);
    }
    const float4 Tf = *((const float4*)&MinvT[row][jb * 4]);

    // Pinv = Minv^T Minv = T T^T ;  W = -0.5 V2 V2^T + V3 ;  A = Pinv W
    const float4 Pinvf = wave_mm_abt(Tf, Tf, lane);
    float4 Wf = wave_mm_abt(V2f, V2f, lane);
    Wf.x = -0.5f * Wf.x + V3f.x;
    Wf.y = -0.5f * Wf.y + V3f.y;
    Wf.z = -0.5f * Wf.z + V3f.z;
    Wf.w = -0.5f * Wf.w + V3f.w;
    float4 prow[4];
    stage_frag(Pinvf, Bbuf0, lane);
    load_rows(Bbuf0, lane, prow);
    stage_frag(Wf, Bbuf1, lane);
    const float4 Af = mm_rows(prow, Bbuf1, lane);

    // ||A||_inf via shuffle butterflies
    float s0 = fabsf(Af.x) + fabsf(Af.y) + fabsf(Af.z) + fabsf(Af.w);
    s0 += __shfl_xor(s0, 1);
    s0 += __shfl_xor(s0, 2);          // row sum in all 4 lanes of the row
    float nrm = s0;
    nrm = fmaxf(nrm, __shfl_xor(nrm, 4));
    nrm = fmaxf(nrm, __shfl_xor(nrm, 8));
    nrm = fmaxf(nrm, __shfl_xor(nrm, 16));
    nrm = fmaxf(nrm, __shfl_xor(nrm, 32));

    // scaling so ||A t / 2^s||_inf <= 0.5
    float nt = nrm * t;
    int s = 0;
    while (nt > 0.5f && s < 30) { nt *= 0.5f; ++s; }
    const float scale = t * exp2f((float)(-s));
    float4 Bh;
    Bh.x = Af.x * scale; Bh.y = Af.y * scale;
    Bh.z = Af.z * scale; Bh.w = Af.w * scale;

    // identity fragment
    float4 idf;
    idf.x = (row == 4 * jb + 0) ? 1.0f : 0.0f;
    idf.y = (row == 4 * jb + 1) ? 1.0f : 0.0f;
    idf.z = (row == 4 * jb + 2) ? 1.0f : 0.0f;
    idf.w = (row == 4 * jb + 3) ? 1.0f : 0.0f;

    // Bh rows hoisted ONCE for the whole Horner loop (A is constant there)
    float4 bhrow[4];
    stage_frag(Bh, Bbuf0, lane);
    load_rows(Bbuf0, lane, bhrow);

    // Horner: P = I + Bh/9 ; then P = I + (Bh P)/d for d = 8..1
    float4 P;
    P.x = idf.x + Bh.x * (1.0f / 9.0f);
    P.y = idf.y + Bh.y * (1.0f / 9.0f);
    P.z = idf.z + Bh.z * (1.0f / 9.0f);
    P.w = idf.w + Bh.w * (1.0f / 9.0f);
#pragma unroll
    for (int d = 8; d >= 1; --d) {
        float* bb = tog ? Bbuf1 : Bbuf0;
        stage_frag(P, bb, lane);
        const float4 c = mm_rows(bhrow, bb, lane); tog ^= 1;
        const float inv = 1.0f / (float)d;
        P.x = idf.x + c.x * inv;
        P.y = idf.y + c.y * inv;
        P.z = idf.z + c.z * inv;
        P.w = idf.w + c.w * inv;
    }
    for (int q = 0; q < s; ++q) {           // squarings: A = B = P, one staging
        float* bb = tog ? Bbuf1 : Bbuf0;
        float4 pr[4];
        stage_frag(P, bb, lane);
        load_rows(bb, lane, pr);
        P = mm_rows(pr, bb, lane); tog ^= 1;
    }

    // --- epilogue: CE = C@E (C padded to 16x16 by duplicating rows) ---
    const int crow = row & 7;
    float4 crow4[4];
#pragma unroll
    for (int q = 0; q < 4; ++q)
        crow4[q] = *((const float4*)(C_w + crow * 16 + q * 4));
    {
        float* bb = tog ? Bbuf1 : Bbuf0;
        stage_frag(P, bb, lane);
        // CEf computed below with A-row = C row (identical values to shuffle)
    }
    const float4 CEf = mm_rows(crow4, tog ? Bbuf1 : Bbuf0, lane); tog ^= 1;

    // CEf rows staged once, shared by Mrow and G
    float4 cerow[4];
    {
        float* bb = tog ? Bbuf1 : Bbuf0;
        stage_frag(CEf, bb, lane);
        load_rows(bb, lane, cerow); tog ^= 1;
    }
    const float4 covf = *((const float4*)(cov0 + row * 16 + jb * 4));
    {
        float* bb = tog ? Bbuf1 : Bbuf0;
        stage_frag(covf, bb, lane);
    }
    const float4 Mrowf = mm_rows(cerow, tog ? Bbuf1 : Bbuf0, lane); tog ^= 1;
    float4 Bwf = make_float4(0.f, 0.f, 0.f, 0.f);
    if (jb < 2) Bwf = *((const float4*)(B_w + row * 8 + jb * 4));
    {
        float* bb = tog ? Bbuf1 : Bbuf0;
        stage_frag(Bwf, bb, lane);
    }
    const float4 Gf = mm_rows(cerow, tog ? Bbuf1 : Bbuf0, lane); tog ^= 1;
    const float4 x0f = *((const float4*)(x0 + jb * 4));
    float yp = CEf.x * x0f.x + CEf.y * x0f.y + CEf.z * x0f.z + CEf.w * x0f.w;
    yp += __shfl_xor(yp, 1);
    yp += __shfl_xor(yp, 2);                // full dot in row lanes

    if (row < 8) {
        *((float4*)(CE_g   + k * 128 + row * 16 + jb * 4)) = CEf;
        *((float4*)(Mrow_g + k * 128 + row * 16 + jb * 4)) = Mrowf;
        if (jb < 2) *((float4*)(G_g + k * 64 + row * 8 + jb * 4)) = Gf;
        if (jb == 0) y1_g[k * 8 + row] = yp;
    }
}

// ---------------------------------------------------------------------------
// Phase 2 (fused covar + mean): grid (11, 320) x 256 thr.  VERBATIM the
// 102.0/99.5-µs version (padded LDS strides, 2-row register blocking).
// ---------------------------------------------------------------------------
#define CEP 132   // padded CE row stride in floats (132 mod 32 = 4)
#define MIP 20    // padded Mi row stride in floats (20a mod 32 distinct)

__global__ void k_phase2(const float* __restrict__ Mrow_g,
                         const float* __restrict__ CE_g,
                         const float* __restrict__ y1_g,
                         const float* __restrict__ G_g,
                         const float* __restrict__ U,
                         const float* __restrict__ dU,
                         const float* __restrict__ D_w,
                         float* __restrict__ out_c1,
                         float* __restrict__ out_cu,
                         float* __restrict__ out_mean) {
    const int bx  = blockIdx.x;   // 0..10
    const int i   = blockIdx.y;   // 0..319
    const int tid = threadIdx.x;

    if (bx < 10) {
        __shared__ float CEj[32 * CEP];   // 16896 B, padded
        __shared__ float Mi[8 * MIP];     // 640 B, padded
        const int jg = bx;
        {   // staging: 32 j-rows of 128 floats -> padded rows of CEP
            const float4* srcC = (const float4*)(CE_g + jg * 4096);
#pragma unroll
            for (int r = 0; r < 4; ++r) {
                const int t = tid + 256 * r;   // 0..1023 float4s
                const int j = t >> 5;          // 0..31
                const int q = t & 31;          // float4 within row
                *((float4*)&CEj[j * CEP + q * 4]) = srcC[t];
            }
            if (tid < 32) {
                const int a = tid >> 2, q = tid & 3;
                *((float4*)&Mi[a * MIP + q * 4]) =
                    ((const float4*)(Mrow_g + i * 128))[tid];
            }
        }
        __syncthreads();

        const int jj  = tid >> 3;         // 0..31
        const int rem = tid & 7;
        const int a0  = rem >> 1;         // 0..3 (this thread also does a0+4)
        const int bg  = rem & 1;          // 0..1 (4 b's each)
        const float* ce = CEj + jj * CEP + bg * 64;
        const float* m0 = Mi + a0 * MIP;
        const float* m1 = Mi + (a0 + 4) * MIP;
        float r0[4], r1[4];
#pragma unroll
        for (int b = 0; b < 4; ++b) {
            float acc0 = 0.0f, acc1 = 0.0f;
#pragma unroll
            for (int l = 0; l < 16; ++l) {
                const float c = ce[b * 16 + l];
                acc0 += m0[l] * c;
                acc1 += m1[l] * c;
            }
            r0[b] = acc0; r1[b] = acc1;
        }
        const int j = jg * 32 + jj;
        float* dst = out_c1 + ((size_t)(i * 320 + j)) * 64;
        *((float4*)(dst + a0 * 8 + bg * 4)) =
            make_float4(r0[0], r0[1], r0[2], r0[3]);
        *((float4*)(dst + (a0 + 4) * 8 + bg * 4)) =
            make_float4(r1[0], r1[1], r1[2], r1[3]);

        if (tid < 32) {
            const int jx = jg * 32 + tid;
            const float d = (float)(i - jx) * STEPF;
            out_cu[i * 320 + jx] = expf(-50.0f * d * d);  // LT=0.1 -> 50
        }
    } else {
        __shared__ float part[256];
        const int m  = tid & 7;
        const int js = tid >> 3;          // 0..31
        float acc = 0.0f;
        if (i > 0) {
            for (int j = js; j <= i; j += 32) {
                const float w = ((j == 0) || (j == i)) ? 0.5f : 1.0f;
                const float4* Gr = (const float4*)(G_g + (i - j) * 64 + m * 8);
                const float4* Ur = (const float4*)(U + j * 8);
                const float4 g0 = Gr[0], g1 = Gr[1];
                const float4 u0 = Ur[0], u1 = Ur[1];
                float d = g0.x * u0.x + g0.y * u0.y + g0.z * u0.z + g0.w * u0.w
                        + g1.x * u1.x + g1.y * u1.y + g1.z * u1.z + g1.w * u1.w;
                acc += w * d;
            }
        }
        part[tid] = acc;
        __syncthreads();
#pragma unroll
        for (int off = 128; off >= 8; off >>= 1) {
            if (tid < off) part[tid] += part[tid + off];
            __syncthreads();
        }
        if (tid < 8) {
            float t3 = 0.0f;
#pragma unroll
            for (int p = 0; p < 8; ++p) t3 += D_w[tid * 8 + p] * dU[i * 8 + p];
            out_mean[i * 8 + tid] = y1_g[i * 8 + tid] + STEPF * part[tid] + t3;
        }
    }
}

// ---------------------------------------------------------------------------
extern "C" void kernel_launch(void* const* d_in, const int* in_sizes, int n_in,
                              void* d_out, int out_size, void* d_ws, size_t ws_size,
                              hipStream_t stream) {
    const float* V1r  = (const float*)d_in[0];
    const float* V2r  = (const float*)d_in[1];
    const float* V3r  = (const float*)d_in[2];
    const float* B_w  = (const float*)d_in[3];
    const float* C_w  = (const float*)d_in[4];
    const float* D_w  = (const float*)d_in[5];
    const float* x0   = (const float*)d_in[6];
    const float* cov0 = (const float*)d_in[7];
    const float* U    = (const float*)d_in[8];
    const float* dU   = (const float*)d_in[9];

    float* ws   = (float*)d_ws;
    float* CE   = ws;             // 320*128 = 40960
    float* Mrow = CE + 40960;     // 40960
    float* G    = Mrow + 40960;   // 320*64 = 20480
    float* y1   = G + 20480;      // 2560

    float* out      = (float*)d_out;
    float* out_mean = out;                      // 320*8
    float* out_c1   = out + 2560;               // 320*320*64
    float* out_cu   = out + 2560 + 320*320*64;  // 320*320

    k_phase1<<<NT, 64, 0, stream>>>(V1r, V2r, V3r, C_w, B_w, cov0, x0,
                                    CE, Mrow, G, y1);
    k_phase2<<<dim3(11, NT), 256, 0, stream>>>(Mrow, CE, y1, G, U, dU, D_w,
                                               out_c1, out_cu, out_mean);
}